// Round 11
// baseline (382.873 us; speedup 1.0000x reference)
//
#include <hip/hip_runtime.h>
#include <hip/hip_bf16.h>
#include <math.h>

// Problem constants: B=2, C=128, T=512, F=64 -> N=B*F=128 sequences, NT=65536 rows.
// GRU: G=4 groups, D=32, 3D=96. MHA: H=4 heads, Dh=32, window=100.
// Workspace layout (needs ~100.8 MB):
//   seq  fp32 [65536][128]  @ 0          (33,554,432 B)  residual stream
//   tmpb bf16 [65536][128]  @ 33554432   (16,777,216 B)  ln1/ln2 output
//   big  bf16 [65536][384]  @ 50331648   (50,331,648 B)  xp (grouped: [(n,t,g)][96]) then qkv
//   wbuf bf16 weights       @ 100663296  (~137 KB)

typedef __attribute__((ext_vector_type(8))) short short8;
typedef __attribute__((ext_vector_type(4))) float f32x4;
typedef __attribute__((ext_vector_type(2))) float f32x2;

__device__ __forceinline__ float bflo(unsigned int u) { return __uint_as_float(u << 16); }
__device__ __forceinline__ float bfhi(unsigned int u) { return __uint_as_float(u & 0xffff0000u); }
__device__ __forceinline__ float bf2f(unsigned short u) { return __uint_as_float(((unsigned int)u) << 16); }
__device__ __forceinline__ unsigned short f2bf(float f) {
  __hip_bfloat16 h = __float2bfloat16(f);
  return *reinterpret_cast<unsigned short*>(&h);
}

// global -> LDS hardware DMA, 16 B per lane. LDS dest = uniform base + lane*16; global
// source is per-lane (this is how we choose the LDS flattening).
typedef __attribute__((address_space(1))) const unsigned int uint_g;
typedef __attribute__((address_space(3))) unsigned int uint_l;
__device__ __forceinline__ void glds16(const void* g, void* l) {
  __builtin_amdgcn_global_load_lds((uint_g*)g, (uint_l*)l, 16, 0, 0);
}

// ---------------- transpose x[B,C,T,F] -> seq[(b*64+f)][t][c], fused ln1 + weight cvt ----
// Round 10 consolidation: weight fp32->bf16 conversion folded in (first 68608 global
// threads) — removes the standalone cvt launch. ln1 fusion as in round 10.
__global__ __launch_bounds__(256) void transpose_in_ln_kernel(const float* __restrict__ x,
                                                              float* __restrict__ seq,
                                                              const float* __restrict__ gam,
                                                              const float* __restrict__ bet,
                                                              unsigned short* __restrict__ out,
                                                              const float* __restrict__ wih,
                                                              unsigned short* __restrict__ wih_b,
                                                              const float* __restrict__ inw,
                                                              unsigned short* __restrict__ inw_b,
                                                              const float* __restrict__ outw,
                                                              unsigned short* __restrict__ outw_b) {
  // fused weight conversion (3072 + 49152 + 16384 = 68608 elements)
  {
    int g_ = blockIdx.x * 256 + threadIdx.x;
    if (g_ < 3072) wih_b[g_] = f2bf(wih[g_]);
    else if (g_ < 52224) inw_b[g_ - 3072] = f2bf(inw[g_ - 3072]);
    else if (g_ < 68608) outw_b[g_ - 52224] = f2bf(outw[g_ - 52224]);
  }

  __shared__ float tile[128 * 65];
  int b = blockIdx.x >> 9;
  int t = blockIdx.x & 511;
  for (int i = threadIdx.x; i < 128 * 64; i += 256) {
    int c = i >> 6, f = i & 63;
    tile[c * 65 + f] = x[(((size_t)(b * 128 + c)) * 512 + t) * 64 + f];
  }
  __syncthreads();
  for (int i = threadIdx.x; i < 64 * 128; i += 256) {
    int f = i >> 7, c = i & 127;
    seq[(((size_t)(b * 64 + f)) * 512 + t) * 128 + c] = tile[c * 65 + f];
  }

  // fused ln1: thread (f = tid>>2, q = tid&3) reduces channels q*32..q*32+31 of row f
  const int f = threadIdx.x >> 2, q = threadIdx.x & 3;
  float s = 0.f, ss = 0.f;
  #pragma unroll
  for (int u = 0; u < 32; ++u) {
    float v = tile[(q * 32 + u) * 65 + f];
    s += v; ss += v * v;
  }
  s += __shfl_xor(s, 1); s += __shfl_xor(s, 2);
  ss += __shfl_xor(ss, 1); ss += __shfl_xor(ss, 2);
  float mean = s * (1.f / 128.f);
  float var = ss * (1.f / 128.f) - mean * mean;
  float rs = rsqrtf(var + 1e-5f);

  unsigned int* orow = (unsigned int*)(out + (((size_t)(b * 64 + f)) * 512 + t) * 128);
  #pragma unroll
  for (int u = 0; u < 8; ++u) {
    int c0 = q * 32 + u * 4;
    float4 gg = ((const float4*)gam)[c0 >> 2];
    float4 bb = ((const float4*)bet)[c0 >> 2];
    float v0 = tile[(c0 + 0) * 65 + f], v1 = tile[(c0 + 1) * 65 + f];
    float v2 = tile[(c0 + 2) * 65 + f], v3 = tile[(c0 + 3) * 65 + f];
    float o0 = (v0 - mean) * rs * gg.x + bb.x;
    float o1 = (v1 - mean) * rs * gg.y + bb.y;
    float o2 = (v2 - mean) * rs * gg.z + bb.z;
    float o3 = (v3 - mean) * rs * gg.w + bb.w;
    orow[(c0 >> 1) + 0] = ((unsigned int)f2bf(o1) << 16) | (unsigned int)f2bf(o0);
    orow[(c0 >> 1) + 1] = ((unsigned int)f2bf(o3) << 16) | (unsigned int)f2bf(o2);
  }
}

__global__ __launch_bounds__(256) void transpose_out_kernel(const float* __restrict__ seq, float* __restrict__ out) {
  __shared__ float tile[128 * 65];
  int b = blockIdx.x >> 9;
  int t = blockIdx.x & 511;
  for (int i = threadIdx.x; i < 64 * 128; i += 256) {
    int f = i >> 7, c = i & 127;
    tile[c * 65 + f] = seq[(((size_t)(b * 64 + f)) * 512 + t) * 128 + c];
  }
  __syncthreads();
  for (int i = threadIdx.x; i < 128 * 64; i += 256) {
    int c = i >> 6, f = i & 63;
    out[(((size_t)(b * 128 + c)) * 512 + t) * 64 + f] = tile[c * 65 + f];
  }
}

// ---------------- layernorm over C=128, fp32 in -> bf16 out (ln2) ----------------
__global__ __launch_bounds__(256) void ln_kernel(const float* __restrict__ in, const float* __restrict__ g,
                                                 const float* __restrict__ b, unsigned short* __restrict__ out) {
  int row = blockIdx.x * 4 + (threadIdx.x >> 6);
  int lane = threadIdx.x & 63;
  float2 v = ((const float2*)(in + (size_t)row * 128))[lane];
  float s = v.x + v.y, ss = v.x * v.x + v.y * v.y;
  #pragma unroll
  for (int off = 32; off > 0; off >>= 1) {
    s += __shfl_xor(s, off);
    ss += __shfl_xor(ss, off);
  }
  float mean = s * (1.f / 128.f);
  float var = ss * (1.f / 128.f) - mean * mean;
  float rs = rsqrtf(var + 1e-5f);
  float2 gg = ((const float2*)g)[lane];
  float2 bb = ((const float2*)b)[lane];
  float o0 = (v.x - mean) * rs * gg.x + bb.x;
  float o1 = (v.y - mean) * rs * gg.y + bb.y;
  unsigned int packed = ((unsigned int)f2bf(o1) << 16) | (unsigned int)f2bf(o0);
  ((unsigned int*)(out + (size_t)row * 128))[lane] = packed;
}

// ---------------- MFMA GEMM: out[m][n] (+)= sum_k A[m][k]*W[n][k] + bias[n] ----------------
// A bf16 [M][K] (M = gridDim.x*128), W bf16 [Ncols][K]. MODE 0: store bf16 (stride Ncols).
// MODE 1: outF[m*128+n] += v (fp32).
template <int K, int MODE>
__global__ __launch_bounds__(256) void gemm_mfma(const unsigned short* __restrict__ A,
                                                 const unsigned short* __restrict__ W,
                                                 const float* __restrict__ bias,
                                                 unsigned short* __restrict__ outB,
                                                 float* __restrict__ outF, int Ncols) {
  const int tid = threadIdx.x;
  const int wave = tid >> 6, lane = tid & 63;
  const int wy = wave >> 1, wx = wave & 1;
  const int lr = lane & 15, lq = lane >> 4;
  const int m0 = blockIdx.x * 128 + wy * 64;
  const int n0 = blockIdx.y * 128 + wx * 64;

  f32x4 acc[4][4];
  #pragma unroll
  for (int i = 0; i < 4; ++i)
    #pragma unroll
    for (int j = 0; j < 4; ++j) acc[i][j] = f32x4{0.f, 0.f, 0.f, 0.f};

  const short8 zfrag = short8{0, 0, 0, 0, 0, 0, 0, 0};

  #pragma unroll
  for (int kk = 0; kk < K; kk += 32) {
    short8 af[4], bfq[4];
    #pragma unroll
    for (int i = 0; i < 4; ++i)
      af[i] = *(const short8*)(A + (size_t)(m0 + i * 16 + lr) * K + kk + lq * 8);
    #pragma unroll
    for (int j = 0; j < 4; ++j) {
      int wr = n0 + j * 16 + lr;
      bfq[j] = (wr < Ncols) ? *(const short8*)(W + (size_t)wr * K + kk + lq * 8) : zfrag;
    }
    #pragma unroll
    for (int i = 0; i < 4; ++i)
      #pragma unroll
      for (int j = 0; j < 4; ++j)
        acc[i][j] = __builtin_amdgcn_mfma_f32_16x16x32_bf16(af[i], bfq[j], acc[i][j], 0, 0, 0);
  }

  #pragma unroll
  for (int j = 0; j < 4; ++j) {
    int col = n0 + j * 16 + lr;
    if (col < Ncols) {
      float bb = bias[col];
      #pragma unroll
      for (int i = 0; i < 4; ++i) {
        #pragma unroll
        for (int r = 0; r < 4; ++r) {
          int row = m0 + i * 16 + lq * 4 + r;
          float v = acc[i][j][r] + bb;
          if (MODE == 0)
            outB[(size_t)row * Ncols + col] = f2bf(v);
          else
            outF[(size_t)row * 128 + col] += v;
        }
      }
    }
  }
}

// ---------------- grouped GRU scan over T=512 — LDS-DMA double-buffered chunks ----------------
// Best measured variant (138.5 us, rounds 6/7/10). Three alternative designs (r8 XOR-systolic
// 145.9, r9 split-K 151.1) regressed — per-step ~650 cyc is an invariant of this recurrence
// on this HW per current evidence; do not restructure without disasm evidence.
__global__ __launch_bounds__(64, 1) void gru_kernel(const unsigned short* __restrict__ xp,
                                                    const float* __restrict__ whh,
                                                    const float* __restrict__ bhh,
                                                    float* __restrict__ seq) {
  const int l = threadIdx.x;
  const int half = l >> 5, d = l & 31;
  const int blk = blockIdx.x;           // 0..255
  const int chain = blk * 2 + half;     // chains 2b,2b+1 share n
  const int n = chain >> 2;
  const int g0 = (blk * 2) & 3;

  const float LOG2E = 1.4426950408889634f;
  const float T2LOG2E = 2.8853900817779268f;

  __shared__ __align__(16) unsigned char stage[2][6144];  // per buf: xp0 2K | xp1 2K | seq 2K
  __shared__ __align__(16) float h_lds[2][64];
  h_lds[0][l] = 0.f;

  f32x2 wr2[16], wz2[16], wn2[16];
  #pragma unroll
  for (int u = 0; u < 16; ++u) {
    float2 a = *(const float2*)(whh + (size_t)d * 32 + u * 2);
    float2 b = *(const float2*)(whh + (size_t)(32 + d) * 32 + u * 2);
    float2 c = *(const float2*)(whh + (size_t)(64 + d) * 32 + u * 2);
    wr2[u] = f32x2{a.x * LOG2E, a.y * LOG2E};
    wz2[u] = f32x2{b.x * LOG2E, b.y * LOG2E};
    wn2[u] = f32x2{c.x * T2LOG2E, c.y * T2LOG2E};
  }
  // Pins are LOAD-BEARING: they keep the loop free of remat vmem loads, which would corrupt
  // the vmcnt counts below.
  #pragma unroll
  for (int u = 0; u < 16; ++u)
    asm volatile("" : "+v"(wr2[u]), "+v"(wz2[u]), "+v"(wn2[u]));

  float br = bhh[d] * LOG2E, bz = bhh[32 + d] * LOG2E, bn = bhh[64 + d] * T2LOG2E;
  asm volatile("" : "+v"(br), "+v"(bz), "+v"(bn));

  const char* xg = (const char*)xp;
  const size_t cb0 = ((size_t)n * 2048 + g0) * 192;
  const size_t cb1 = ((size_t)n * 2048 + g0 + 1) * 192;
  const int fa = l * 16;
  const int oxa = (fa / 192) * 768 + (fa % 192);
  const int fb = 1024 + l * 16;
  const int oxb = (fb / 192) * 768 + (fb % 192);
  const char* px0a = xg + cb0 + oxa;
  const char* px0b = xg + cb0 + oxb;
  const char* px1a = xg + cb1 + oxa;
  const char* px1b = xg + cb1 + oxb;
  const int osa = (l >> 4) * 512 + (l & 15) * 16;
  const size_t sqb0 = ((size_t)n * 512 * 128 + (size_t)g0 * 32) * 4;
  const char* psa = (const char*)seq + sqb0 + osa;
  const char* psb = psa + 2048;  // rows 4..7

  float* sb = seq + (size_t)n * 512 * 128 + g0 * 32 + l;  // per-lane output addr (t=0)

  glds16(px0a, stage[0] + 0);
  glds16(px0b, stage[0] + 1024);
  glds16(px1a, stage[0] + 2048);
  glds16(px1b, stage[0] + 3072);
  glds16(psa,  stage[0] + 4096);
  glds16(psb,  stage[0] + 5120);

  float hprev = 0.f;

  for (int c = 0; c < 64; ++c) {
    const int cur = c & 1;
    if (c < 63) {
      const size_t xo = (size_t)(c + 1) * 6144;
      const size_t so = (size_t)(c + 1) * 4096;
      unsigned char* nb = stage[cur ^ 1];
      glds16(px0a + xo, nb + 0);
      glds16(px0b + xo, nb + 1024);
      glds16(px1a + xo, nb + 2048);
      glds16(px1b + xo, nb + 3072);
      glds16(psa + so,  nb + 4096);
      glds16(psb + so,  nb + 5120);
    }
    __builtin_amdgcn_sched_barrier(0);
    if (c == 0)       asm volatile("s_waitcnt vmcnt(6)" ::: "memory");
    else if (c == 63) asm volatile("s_waitcnt vmcnt(8)" ::: "memory");
    else              asm volatile("s_waitcnt vmcnt(14)" ::: "memory");
    __builtin_amdgcn_sched_barrier(0);

    const unsigned char* scur = stage[cur];
    #pragma unroll
    for (int p = 0; p < 8; ++p) {
      const int t = c * 8 + p;

      const f32x4* hsrc = (const f32x4*)&h_lds[p & 1][half * 32];
      f32x2 ar0 = f32x2{br, 0.f}, ar1 = f32x2{0.f, 0.f};
      f32x2 az0 = f32x2{bz, 0.f}, az1 = f32x2{0.f, 0.f};
      f32x2 an0 = f32x2{bn, 0.f}, an1 = f32x2{0.f, 0.f};
      #pragma unroll
      for (int u = 0; u < 8; ++u) {
        f32x4 h4 = hsrc[u];
        f32x2 hlo = f32x2{h4.x, h4.y};
        f32x2 hhi = f32x2{h4.z, h4.w};
        ar0 += wr2[2 * u] * hlo; ar1 += wr2[2 * u + 1] * hhi;
        az0 += wz2[2 * u] * hlo; az1 += wz2[2 * u + 1] * hhi;
        an0 += wn2[2 * u] * hlo; an1 += wn2[2 * u + 1] * hhi;
      }
      f32x2 arv = ar0 + ar1, azv = az0 + az1, anv = an0 + an1;
      float accr = arv.x + arv.y;
      float accz = azv.x + azv.y;
      float accn = anv.x + anv.y;

      const unsigned short* xrow = (const unsigned short*)(scur + half * 2048 + p * 192);
      float xr = bf2f(xrow[d]) * LOG2E;
      float xz = bf2f(xrow[32 + d]) * LOG2E;
      float xn2 = bf2f(xrow[64 + d]) * T2LOG2E;
      float sv0 = *(const float*)(scur + 4096 + p * 256 + (l << 2));

      float r = __builtin_amdgcn_rcpf(1.f + __builtin_amdgcn_exp2f(-(xr + accr)));
      float z = __builtin_amdgcn_rcpf(1.f + __builtin_amdgcn_exp2f(-(xz + accz)));
      float e2 = __builtin_amdgcn_exp2f(xn2 + r * accn);
      float nn = 1.f - 2.f * __builtin_amdgcn_rcpf(e2 + 1.f);  // tanh, saturates at +/-1
      float hnew = z * (hprev - nn) + nn;
      hprev = hnew;

      h_lds[(p + 1) & 1][l] = hnew;        // in-order DS pipe: next step's reads see this
      sb[(size_t)t * 128] = sv0 + hnew;    // 64 lanes -> one coalesced 256 B store
    }
  }
}

// ---------------- fused windowed attention + out-projection ----------------
// grid (T/64=8, N=128), 256 threads = 4 waves; wave w owns q-subtile [qbase+w*16, +16).
// Per head h (loop): stage K[192x32] (glds) + V^T[32x200] (scatter), r7's MFMA flash
// (S=mfma(Q,K), P=exp2 masked no-max, O^T=mfma(V^T,P)), normalize, write bf16 into LDS
// OT[64][132] at channel h*32+d. After the 4-head loop: out-projection from OT with the
// gemm_mfma operand convention (A=OT rows, W=outw_b [128][128]), seq += result + bo.
// Eliminates the standalone out-proj gemm: 16 MB tmpb write + 16 MB read + one launch.
__global__ __launch_bounds__(256) void attn_oproj_kernel(const unsigned short* __restrict__ qkv,
                                                         const unsigned short* __restrict__ outw_b,
                                                         const float* __restrict__ outb,
                                                         float* __restrict__ seq) {
  const int qbase = blockIdx.x * 64;
  const int n = blockIdx.y;
  const int tid = threadIdx.x;
  const int w = tid >> 6, lane = tid & 63;
  const int lr = lane & 15, lq = lane >> 4;
  const int ws0 = max(0, qbase - 100);

  const int KROWS = 192;   // staged key rows (>= max window 164, rounded for DMA)
  const int VPITCH = 200;  // VT row pitch in u16 (breaks bank conflicts, 16B-aligned rows)
  const int PPITCH = 40;   // PL row pitch in u16
  const int OPITCH = 132;  // OT row pitch in u16

  __shared__ unsigned short KL[192 * 32];      // K rows [key][d] (per head)
  __shared__ unsigned short VT[32 * 200];      // V transposed [d][key] (per head)
  __shared__ unsigned short PL[4][16 * 40];    // per-wave P tile
  __shared__ float LL[64];                     // per-wave row sums
  __shared__ unsigned short OT[64 * 132];      // attn output tile [q][128 ch], bf16

  const char* qkvb = (const char*)qkv;
  const size_t rowb = ((size_t)(n * 512 + ws0)) * 768;  // window base row, bytes
  const int wq0 = qbase + w * 16;

  const float SCL2 = 0.17677669529663687f * 1.4426950408889634f;  // 1/sqrt(32) * log2e
  const int lo = max(0, wq0 - 100) - ws0;
  const int hi = wq0 + 15 - ws0;
  const int kc0 = lo >> 5, kc1 = hi >> 5;
  unsigned short* plw = PL[w];

  for (int h = 0; h < 4; ++h) {
    if (h) __syncthreads();  // all waves done reading KL/VT of previous head

    // stage K rows via global_load_lds: chunk c (16 B) -> KL byte c*16; row c/4, piece c%4
    #pragma unroll
    for (int it = 0; it < 3; ++it) {
      int c = w * 192 + it * 64 + lane;
      const char* src = qkvb + rowb + (size_t)(c >> 2) * 768 + 256 + h * 64 + (size_t)(c & 3) * 16;
      glds16(src, (char*)KL + w * 3072 + it * 1024);
    }
    // stage V transposed: thread k reads V row, scatters 32 b16 into VT[d][k]
    if (tid < KROWS) {
      const unsigned int* vsrc = (const unsigned int*)(qkvb + rowb + (size_t)tid * 768 + 512 + h * 64);
      #pragma unroll
      for (int u = 0; u < 16; ++u) {
        unsigned int vv = vsrc[u];
        VT[(2 * u) * VPITCH + tid] = (unsigned short)(vv & 0xffff);
        VT[(2 * u + 1) * VPITCH + tid] = (unsigned short)(vv >> 16);
      }
    }
    // Q A-frag: lane holds Q[q = wq0+lr][d = lq*8..+7]
    short8 qfrag = *(const short8*)(qkvb + ((size_t)(n * 512 + wq0 + lr)) * 768 + h * 64 + lq * 16);
    __syncthreads();  // compiler drains vmcnt (DMA) + lgkm (VT writes) before barrier

    f32x4 oacc0 = f32x4{0.f, 0.f, 0.f, 0.f};
    f32x4 oacc1 = f32x4{0.f, 0.f, 0.f, 0.f};
    float lsum[4] = {0.f, 0.f, 0.f, 0.f};

    for (int kc = kc0; kc <= kc1; ++kc) {
      #pragma unroll
      for (int sub = 0; sub < 2; ++sub) {
        const int kt = kc * 2 + sub;
        short8 kfrag = *(const short8*)(KL + (kt * 16 + lr) * 32 + lq * 8);
        f32x4 s4 = __builtin_amdgcn_mfma_f32_16x16x32_bf16(qfrag, kfrag,
                                                           f32x4{0.f, 0.f, 0.f, 0.f}, 0, 0, 0);
        const int tk = ws0 + kt * 16 + lr;
        #pragma unroll
        for (int r = 0; r < 4; ++r) {
          const int tq = wq0 + lq * 4 + r;
          bool ok = (tk <= tq) && (tk + 100 >= tq);
          float p = ok ? __builtin_amdgcn_exp2f(s4[r] * SCL2) : 0.f;
          lsum[r] += p;
          plw[(lq * 4 + r) * PPITCH + sub * 16 + lr] = f2bf(p);
        }
      }
      // PV: same-wave DS in-order — reads see the writes above
      short8 pfrag = *(const short8*)(plw + lr * PPITCH + lq * 8);
      short8 vf0 = *(const short8*)(VT + lr * VPITCH + kc * 32 + lq * 8);
      short8 vf1 = *(const short8*)(VT + (16 + lr) * VPITCH + kc * 32 + lq * 8);
      oacc0 = __builtin_amdgcn_mfma_f32_16x16x32_bf16(vf0, pfrag, oacc0, 0, 0, 0);
      oacc1 = __builtin_amdgcn_mfma_f32_16x16x32_bf16(vf1, pfrag, oacc1, 0, 0, 0);
    }

    // row-sum butterfly over the 16 key-columns, then route to q=lr lanes via LDS
    #pragma unroll
    for (int r = 0; r < 4; ++r) {
      float v = lsum[r];
      v += __shfl_xor(v, 1); v += __shfl_xor(v, 2);
      v += __shfl_xor(v, 4); v += __shfl_xor(v, 8);
      lsum[r] = v;
    }
    if (lr == 0) {
      #pragma unroll
      for (int r = 0; r < 4; ++r) LL[w * 16 + lq * 4 + r] = lsum[r];
    }
    float rl = __builtin_amdgcn_rcpf(LL[w * 16 + lr]);  // same-wave DS in-order

    // O^T layout: lane holds O[d = dt*16 + lq*4 + r][q = lr]. Write bf16 into OT row
    // q = w*16+lr at channel h*32 + d; 4 consecutive d -> one b64 write (8B-aligned).
    {
      unsigned short* orow = OT + (w * 16 + lr) * OPITCH + h * 32 + lq * 4;
      uint2 pk0;
      pk0.x = ((unsigned int)f2bf(oacc0[1] * rl) << 16) | f2bf(oacc0[0] * rl);
      pk0.y = ((unsigned int)f2bf(oacc0[3] * rl) << 16) | f2bf(oacc0[2] * rl);
      *(uint2*)orow = pk0;
      uint2 pk1;
      pk1.x = ((unsigned int)f2bf(oacc1[1] * rl) << 16) | f2bf(oacc1[0] * rl);
      pk1.y = ((unsigned int)f2bf(oacc1[3] * rl) << 16) | f2bf(oacc1[2] * rl);
      *(uint2*)(orow + 16) = pk1;
    }
  }

  __syncthreads();  // OT complete across all waves/heads

  // out-projection: wave w handles rows [w*16, +16) of the 64-row tile, all 128 cols.
  // Same operand convention as gemm_mfma: A row=lr / C row=lq*4+r, col=lr.
  f32x4 acc[8];
  #pragma unroll
  for (int j = 0; j < 8; ++j) acc[j] = f32x4{0.f, 0.f, 0.f, 0.f};
  #pragma unroll
  for (int kk = 0; kk < 4; ++kk) {
    short8 af = *(const short8*)(OT + (w * 16 + lr) * OPITCH + kk * 32 + lq * 8);
    #pragma unroll
    for (int j = 0; j < 8; ++j) {
      short8 wf = *(const short8*)(outw_b + (size_t)(j * 16 + lr) * 128 + kk * 32 + lq * 8);
      acc[j] = __builtin_amdgcn_mfma_f32_16x16x32_bf16(af, wf, acc[j], 0, 0, 0);
    }
  }
  #pragma unroll
  for (int j = 0; j < 8; ++j) {
    int col = j * 16 + lr;
    float bb = outb[col];
    #pragma unroll
    for (int r = 0; r < 4; ++r) {
      size_t row = (size_t)n * 512 + qbase + w * 16 + lq * 4 + r;
      seq[row * 128 + col] += acc[j][r] + bb;
    }
  }
}

// ---------------- host launcher ----------------
extern "C" void kernel_launch(void* const* d_in, const int* in_sizes, int n_in,
                              void* d_out, int out_size, void* d_ws, size_t ws_size,
                              hipStream_t stream) {
  const float* x      = (const float*)d_in[0];
  const float* ln1_g  = (const float*)d_in[1];
  const float* ln1_b  = (const float*)d_in[2];
  const float* wih    = (const float*)d_in[3];
  const float* whh    = (const float*)d_in[4];
  const float* bih    = (const float*)d_in[5];
  const float* bhh    = (const float*)d_in[6];
  const float* ln2_g  = (const float*)d_in[7];
  const float* ln2_b  = (const float*)d_in[8];
  const float* inw    = (const float*)d_in[9];
  const float* inb    = (const float*)d_in[10];
  const float* outw   = (const float*)d_in[11];
  const float* outb   = (const float*)d_in[12];

  char* ws = (char*)d_ws;
  float*          seq   = (float*)ws;                             // 33,554,432 B
  unsigned short* tmpb  = (unsigned short*)(ws + 33554432);       // 16,777,216 B
  unsigned short* big   = (unsigned short*)(ws + 50331648);       // 50,331,648 B
  unsigned short* wih_b = (unsigned short*)(ws + 100663296);      // 3072 elems
  unsigned short* inw_b = wih_b + 3072;                           // 49152 elems
  unsigned short* outw_b = inw_b + 49152;                         // 16384 elems

  // x -> seq + fused ln1 -> tmpb + fused weight conversion
  transpose_in_ln_kernel<<<1024, 256, 0, stream>>>(x, seq, ln1_g, ln1_b, tmpb,
                                                   wih, wih_b, inw, inw_b, outw, outw_b);

  // GRU input projection: [262144][32] x [96][32]^T -> big [(n,t,g)][96]
  gemm_mfma<32, 0><<<dim3(2048, 1), 256, 0, stream>>>(tmpb, wih_b, bih, big, nullptr, 96);

  // GRU scan, seq += h_t  (single-wave blocks, 2 chains/wave)
  gru_kernel<<<256, 64, 0, stream>>>(big, whh, bhh, seq);

  // ln2 -> tmpb
  ln_kernel<<<16384, 256, 0, stream>>>(seq, ln2_g, ln2_b, tmpb);

  // QKV projection: [65536][128] x [384][128]^T -> big [65536][384]
  gemm_mfma<128, 0><<<dim3(512, 3), 256, 0, stream>>>(tmpb, inw_b, inb, big, nullptr, 384);

  // fused attention + out-projection, seq += attn(ln2) @ Wo^T + bo
  attn_oproj_kernel<<<dim3(8, 128), 256, 0, stream>>>(big, outw_b, outb, seq);

  // seq -> d_out
  transpose_out_kernel<<<1024, 256, 0, stream>>>(seq, (float*)d_out);
}

// Round 12
// 353.299 us; speedup vs baseline: 1.0837x; 1.0837x over previous
//
#include <hip/hip_runtime.h>
#include <hip/hip_bf16.h>
#include <math.h>

// Problem constants: B=2, C=128, T=512, F=64 -> N=B*F=128 sequences, NT=65536 rows.
// GRU: G=4 groups, D=32, 3D=96. MHA: H=4 heads, Dh=32, window=100.
// Workspace layout (needs ~100.8 MB):
//   seq  fp32 [65536][128]  @ 0          (33,554,432 B)  residual stream
//   tmpb bf16 [65536][128]  @ 33554432   (16,777,216 B)  ln1/ln2/attn-out
//   big  bf16 [65536][384]  @ 50331648   (50,331,648 B)  xp (grouped: [(n,t,g)][96]) then qkv
//   wbuf bf16 weights       @ 100663296  (~137 KB)

typedef __attribute__((ext_vector_type(8))) short short8;
typedef __attribute__((ext_vector_type(4))) float f32x4;
typedef __attribute__((ext_vector_type(2))) float f32x2;

__device__ __forceinline__ float bflo(unsigned int u) { return __uint_as_float(u << 16); }
__device__ __forceinline__ float bfhi(unsigned int u) { return __uint_as_float(u & 0xffff0000u); }
__device__ __forceinline__ float bf2f(unsigned short u) { return __uint_as_float(((unsigned int)u) << 16); }
__device__ __forceinline__ unsigned short f2bf(float f) {
  __hip_bfloat16 h = __float2bfloat16(f);
  return *reinterpret_cast<unsigned short*>(&h);
}

// global -> LDS hardware DMA, 16 B per lane. LDS dest = uniform base + lane*16; global
// source is per-lane (this is how we choose the LDS flattening).
typedef __attribute__((address_space(1))) const unsigned int uint_g;
typedef __attribute__((address_space(3))) unsigned int uint_l;
__device__ __forceinline__ void glds16(const void* g, void* l) {
  __builtin_amdgcn_global_load_lds((uint_g*)g, (uint_l*)l, 16, 0, 0);
}

// ---------------- transpose x[B,C,T,F] -> seq[(b*64+f)][t][c], fused ln1 + weight cvt ----
__global__ __launch_bounds__(256) void transpose_in_ln_kernel(const float* __restrict__ x,
                                                              float* __restrict__ seq,
                                                              const float* __restrict__ gam,
                                                              const float* __restrict__ bet,
                                                              unsigned short* __restrict__ out,
                                                              const float* __restrict__ wih,
                                                              unsigned short* __restrict__ wih_b,
                                                              const float* __restrict__ inw,
                                                              unsigned short* __restrict__ inw_b,
                                                              const float* __restrict__ outw,
                                                              unsigned short* __restrict__ outw_b) {
  // fused weight conversion (3072 + 49152 + 16384 = 68608 elements)
  {
    int g_ = blockIdx.x * 256 + threadIdx.x;
    if (g_ < 3072) wih_b[g_] = f2bf(wih[g_]);
    else if (g_ < 52224) inw_b[g_ - 3072] = f2bf(inw[g_ - 3072]);
    else if (g_ < 68608) outw_b[g_ - 52224] = f2bf(outw[g_ - 52224]);
  }

  __shared__ float tile[128 * 65];
  int b = blockIdx.x >> 9;
  int t = blockIdx.x & 511;
  for (int i = threadIdx.x; i < 128 * 64; i += 256) {
    int c = i >> 6, f = i & 63;
    tile[c * 65 + f] = x[(((size_t)(b * 128 + c)) * 512 + t) * 64 + f];
  }
  __syncthreads();
  for (int i = threadIdx.x; i < 64 * 128; i += 256) {
    int f = i >> 7, c = i & 127;
    seq[(((size_t)(b * 64 + f)) * 512 + t) * 128 + c] = tile[c * 65 + f];
  }

  // fused ln1: thread (f = tid>>2, q = tid&3) reduces channels q*32..q*32+31 of row f
  const int f = threadIdx.x >> 2, q = threadIdx.x & 3;
  float s = 0.f, ss = 0.f;
  #pragma unroll
  for (int u = 0; u < 32; ++u) {
    float v = tile[(q * 32 + u) * 65 + f];
    s += v; ss += v * v;
  }
  s += __shfl_xor(s, 1); s += __shfl_xor(s, 2);
  ss += __shfl_xor(ss, 1); ss += __shfl_xor(ss, 2);
  float mean = s * (1.f / 128.f);
  float var = ss * (1.f / 128.f) - mean * mean;
  float rs = rsqrtf(var + 1e-5f);

  unsigned int* orow = (unsigned int*)(out + (((size_t)(b * 64 + f)) * 512 + t) * 128);
  #pragma unroll
  for (int u = 0; u < 8; ++u) {
    int c0 = q * 32 + u * 4;
    float4 gg = ((const float4*)gam)[c0 >> 2];
    float4 bb = ((const float4*)bet)[c0 >> 2];
    float v0 = tile[(c0 + 0) * 65 + f], v1 = tile[(c0 + 1) * 65 + f];
    float v2 = tile[(c0 + 2) * 65 + f], v3 = tile[(c0 + 3) * 65 + f];
    float o0 = (v0 - mean) * rs * gg.x + bb.x;
    float o1 = (v1 - mean) * rs * gg.y + bb.y;
    float o2 = (v2 - mean) * rs * gg.z + bb.z;
    float o3 = (v3 - mean) * rs * gg.w + bb.w;
    orow[(c0 >> 1) + 0] = ((unsigned int)f2bf(o1) << 16) | (unsigned int)f2bf(o0);
    orow[(c0 >> 1) + 1] = ((unsigned int)f2bf(o3) << 16) | (unsigned int)f2bf(o2);
  }
}

// ---------------- fused transpose-out + out-projection ----------------
// Round 11 post-mortem: fusing oproj INTO attn cost 4x attn grid parallelism (-18.6 us).
// This block's tile is (b, t) x 64 rows x 128 ch — exactly one out-proj tile — so fuse the
// (r11-verified) oproj MFMA here instead: zero parallelism loss, eliminates the standalone
// oproj gemm's seq RMW (33 MB read + 33 MB write) and one launch. out = transpose(seq +
// attn@Wo^T + bo); seq itself is no longer updated (nothing reads it afterwards).
__global__ __launch_bounds__(256) void transpose_out_oproj_kernel(const float* __restrict__ seq,
                                                                  const unsigned short* __restrict__ attn,
                                                                  const unsigned short* __restrict__ outw_b,
                                                                  const float* __restrict__ outb,
                                                                  float* __restrict__ out) {
  __shared__ float tile[128 * 65];
  int b = blockIdx.x >> 9;
  int t = blockIdx.x & 511;
  const int tid = threadIdx.x;
  const int w = tid >> 6, lane = tid & 63;
  const int lr = lane & 15, lq = lane >> 4;

  // residual tile load (coalesced, unchanged from transpose_out)
  for (int i = tid; i < 64 * 128; i += 256) {
    int f = i >> 7, c = i & 127;
    tile[c * 65 + f] = seq[(((size_t)(b * 64 + f)) * 512 + t) * 128 + c];
  }

  // out-projection: wave w owns rows [w*16, +16). Same operand convention as gemm_mfma
  // (A row=lr; C row=lq*4+r, col=lr) — code verified in round 11 (absmax passed).
  f32x4 acc[8];
  #pragma unroll
  for (int j = 0; j < 8; ++j) acc[j] = f32x4{0.f, 0.f, 0.f, 0.f};
  const unsigned short* arow = attn + (((size_t)(b * 64 + w * 16 + lr)) * 512 + t) * 128;
  #pragma unroll
  for (int kk = 0; kk < 4; ++kk) {
    short8 af = *(const short8*)(arow + kk * 32 + lq * 8);
    #pragma unroll
    for (int j = 0; j < 8; ++j) {
      short8 wf = *(const short8*)(outw_b + (size_t)(j * 16 + lr) * 128 + kk * 32 + lq * 8);
      acc[j] = __builtin_amdgcn_mfma_f32_16x16x32_bf16(af, wf, acc[j], 0, 0, 0);
    }
  }
  __syncthreads();  // residual tile fully loaded before any lane adds into it

  #pragma unroll
  for (int j = 0; j < 8; ++j) {
    int col = j * 16 + lr;
    float bb = outb[col];
    #pragma unroll
    for (int r = 0; r < 4; ++r) {
      int f = w * 16 + lq * 4 + r;        // one writer per (col,f)
      tile[col * 65 + f] += acc[j][r] + bb;
    }
  }
  __syncthreads();

  for (int i = tid; i < 128 * 64; i += 256) {
    int c = i >> 6, f = i & 63;
    out[(((size_t)(b * 128 + c)) * 512 + t) * 64 + f] = tile[c * 65 + f];
  }
}

// ---------------- layernorm over C=128, fp32 in -> bf16 out (ln2) ----------------
__global__ __launch_bounds__(256) void ln_kernel(const float* __restrict__ in, const float* __restrict__ g,
                                                 const float* __restrict__ b, unsigned short* __restrict__ out) {
  int row = blockIdx.x * 4 + (threadIdx.x >> 6);
  int lane = threadIdx.x & 63;
  float2 v = ((const float2*)(in + (size_t)row * 128))[lane];
  float s = v.x + v.y, ss = v.x * v.x + v.y * v.y;
  #pragma unroll
  for (int off = 32; off > 0; off >>= 1) {
    s += __shfl_xor(s, off);
    ss += __shfl_xor(ss, off);
  }
  float mean = s * (1.f / 128.f);
  float var = ss * (1.f / 128.f) - mean * mean;
  float rs = rsqrtf(var + 1e-5f);
  float2 gg = ((const float2*)g)[lane];
  float2 bb = ((const float2*)b)[lane];
  float o0 = (v.x - mean) * rs * gg.x + bb.x;
  float o1 = (v.y - mean) * rs * gg.y + bb.y;
  unsigned int packed = ((unsigned int)f2bf(o1) << 16) | (unsigned int)f2bf(o0);
  ((unsigned int*)(out + (size_t)row * 128))[lane] = packed;
}

// ---------------- MFMA GEMM: out[m][n] (+)= sum_k A[m][k]*W[n][k] + bias[n] ----------------
template <int K, int MODE>
__global__ __launch_bounds__(256) void gemm_mfma(const unsigned short* __restrict__ A,
                                                 const unsigned short* __restrict__ W,
                                                 const float* __restrict__ bias,
                                                 unsigned short* __restrict__ outB,
                                                 float* __restrict__ outF, int Ncols) {
  const int tid = threadIdx.x;
  const int wave = tid >> 6, lane = tid & 63;
  const int wy = wave >> 1, wx = wave & 1;
  const int lr = lane & 15, lq = lane >> 4;
  const int m0 = blockIdx.x * 128 + wy * 64;
  const int n0 = blockIdx.y * 128 + wx * 64;

  f32x4 acc[4][4];
  #pragma unroll
  for (int i = 0; i < 4; ++i)
    #pragma unroll
    for (int j = 0; j < 4; ++j) acc[i][j] = f32x4{0.f, 0.f, 0.f, 0.f};

  const short8 zfrag = short8{0, 0, 0, 0, 0, 0, 0, 0};

  #pragma unroll
  for (int kk = 0; kk < K; kk += 32) {
    short8 af[4], bfq[4];
    #pragma unroll
    for (int i = 0; i < 4; ++i)
      af[i] = *(const short8*)(A + (size_t)(m0 + i * 16 + lr) * K + kk + lq * 8);
    #pragma unroll
    for (int j = 0; j < 4; ++j) {
      int wr = n0 + j * 16 + lr;
      bfq[j] = (wr < Ncols) ? *(const short8*)(W + (size_t)wr * K + kk + lq * 8) : zfrag;
    }
    #pragma unroll
    for (int i = 0; i < 4; ++i)
      #pragma unroll
      for (int j = 0; j < 4; ++j)
        acc[i][j] = __builtin_amdgcn_mfma_f32_16x16x32_bf16(af[i], bfq[j], acc[i][j], 0, 0, 0);
  }

  #pragma unroll
  for (int j = 0; j < 4; ++j) {
    int col = n0 + j * 16 + lr;
    if (col < Ncols) {
      float bb = bias[col];
      #pragma unroll
      for (int i = 0; i < 4; ++i) {
        #pragma unroll
        for (int r = 0; r < 4; ++r) {
          int row = m0 + i * 16 + lq * 4 + r;
          float v = acc[i][j][r] + bb;
          if (MODE == 0)
            outB[(size_t)row * Ncols + col] = f2bf(v);
          else
            outF[(size_t)row * 128 + col] += v;
        }
      }
    }
  }
}

// ---------------- grouped GRU scan over T=512 — LDS-DMA double-buffered chunks ----------------
// Best measured variant (138.5 us, rounds 6/7/10/11). Do not restructure without disasm
// evidence (r8 XOR-systolic 145.9, r9 split-K 151.1 both regressed; ~650 cyc/step invariant).
__global__ __launch_bounds__(64, 1) void gru_kernel(const unsigned short* __restrict__ xp,
                                                    const float* __restrict__ whh,
                                                    const float* __restrict__ bhh,
                                                    float* __restrict__ seq) {
  const int l = threadIdx.x;
  const int half = l >> 5, d = l & 31;
  const int blk = blockIdx.x;           // 0..255
  const int chain = blk * 2 + half;     // chains 2b,2b+1 share n
  const int n = chain >> 2;
  const int g0 = (blk * 2) & 3;

  const float LOG2E = 1.4426950408889634f;
  const float T2LOG2E = 2.8853900817779268f;

  __shared__ __align__(16) unsigned char stage[2][6144];  // per buf: xp0 2K | xp1 2K | seq 2K
  __shared__ __align__(16) float h_lds[2][64];
  h_lds[0][l] = 0.f;

  f32x2 wr2[16], wz2[16], wn2[16];
  #pragma unroll
  for (int u = 0; u < 16; ++u) {
    float2 a = *(const float2*)(whh + (size_t)d * 32 + u * 2);
    float2 b = *(const float2*)(whh + (size_t)(32 + d) * 32 + u * 2);
    float2 c = *(const float2*)(whh + (size_t)(64 + d) * 32 + u * 2);
    wr2[u] = f32x2{a.x * LOG2E, a.y * LOG2E};
    wz2[u] = f32x2{b.x * LOG2E, b.y * LOG2E};
    wn2[u] = f32x2{c.x * T2LOG2E, c.y * T2LOG2E};
  }
  // Pins are LOAD-BEARING: they keep the loop free of remat vmem loads, which would corrupt
  // the vmcnt counts below.
  #pragma unroll
  for (int u = 0; u < 16; ++u)
    asm volatile("" : "+v"(wr2[u]), "+v"(wz2[u]), "+v"(wn2[u]));

  float br = bhh[d] * LOG2E, bz = bhh[32 + d] * LOG2E, bn = bhh[64 + d] * T2LOG2E;
  asm volatile("" : "+v"(br), "+v"(bz), "+v"(bn));

  const char* xg = (const char*)xp;
  const size_t cb0 = ((size_t)n * 2048 + g0) * 192;
  const size_t cb1 = ((size_t)n * 2048 + g0 + 1) * 192;
  const int fa = l * 16;
  const int oxa = (fa / 192) * 768 + (fa % 192);
  const int fb = 1024 + l * 16;
  const int oxb = (fb / 192) * 768 + (fb % 192);
  const char* px0a = xg + cb0 + oxa;
  const char* px0b = xg + cb0 + oxb;
  const char* px1a = xg + cb1 + oxa;
  const char* px1b = xg + cb1 + oxb;
  const int osa = (l >> 4) * 512 + (l & 15) * 16;
  const size_t sqb0 = ((size_t)n * 512 * 128 + (size_t)g0 * 32) * 4;
  const char* psa = (const char*)seq + sqb0 + osa;
  const char* psb = psa + 2048;  // rows 4..7

  float* sb = seq + (size_t)n * 512 * 128 + g0 * 32 + l;  // per-lane output addr (t=0)

  glds16(px0a, stage[0] + 0);
  glds16(px0b, stage[0] + 1024);
  glds16(px1a, stage[0] + 2048);
  glds16(px1b, stage[0] + 3072);
  glds16(psa,  stage[0] + 4096);
  glds16(psb,  stage[0] + 5120);

  float hprev = 0.f;

  for (int c = 0; c < 64; ++c) {
    const int cur = c & 1;
    if (c < 63) {
      const size_t xo = (size_t)(c + 1) * 6144;
      const size_t so = (size_t)(c + 1) * 4096;
      unsigned char* nb = stage[cur ^ 1];
      glds16(px0a + xo, nb + 0);
      glds16(px0b + xo, nb + 1024);
      glds16(px1a + xo, nb + 2048);
      glds16(px1b + xo, nb + 3072);
      glds16(psa + so,  nb + 4096);
      glds16(psb + so,  nb + 5120);
    }
    __builtin_amdgcn_sched_barrier(0);
    if (c == 0)       asm volatile("s_waitcnt vmcnt(6)" ::: "memory");
    else if (c == 63) asm volatile("s_waitcnt vmcnt(8)" ::: "memory");
    else              asm volatile("s_waitcnt vmcnt(14)" ::: "memory");
    __builtin_amdgcn_sched_barrier(0);

    const unsigned char* scur = stage[cur];
    #pragma unroll
    for (int p = 0; p < 8; ++p) {
      const int t = c * 8 + p;

      const f32x4* hsrc = (const f32x4*)&h_lds[p & 1][half * 32];
      f32x2 ar0 = f32x2{br, 0.f}, ar1 = f32x2{0.f, 0.f};
      f32x2 az0 = f32x2{bz, 0.f}, az1 = f32x2{0.f, 0.f};
      f32x2 an0 = f32x2{bn, 0.f}, an1 = f32x2{0.f, 0.f};
      #pragma unroll
      for (int u = 0; u < 8; ++u) {
        f32x4 h4 = hsrc[u];
        f32x2 hlo = f32x2{h4.x, h4.y};
        f32x2 hhi = f32x2{h4.z, h4.w};
        ar0 += wr2[2 * u] * hlo; ar1 += wr2[2 * u + 1] * hhi;
        az0 += wz2[2 * u] * hlo; az1 += wz2[2 * u + 1] * hhi;
        an0 += wn2[2 * u] * hlo; an1 += wn2[2 * u + 1] * hhi;
      }
      f32x2 arv = ar0 + ar1, azv = az0 + az1, anv = an0 + an1;
      float accr = arv.x + arv.y;
      float accz = azv.x + azv.y;
      float accn = anv.x + anv.y;

      const unsigned short* xrow = (const unsigned short*)(scur + half * 2048 + p * 192);
      float xr = bf2f(xrow[d]) * LOG2E;
      float xz = bf2f(xrow[32 + d]) * LOG2E;
      float xn2 = bf2f(xrow[64 + d]) * T2LOG2E;
      float sv0 = *(const float*)(scur + 4096 + p * 256 + (l << 2));

      float r = __builtin_amdgcn_rcpf(1.f + __builtin_amdgcn_exp2f(-(xr + accr)));
      float z = __builtin_amdgcn_rcpf(1.f + __builtin_amdgcn_exp2f(-(xz + accz)));
      float e2 = __builtin_amdgcn_exp2f(xn2 + r * accn);
      float nn = 1.f - 2.f * __builtin_amdgcn_rcpf(e2 + 1.f);  // tanh, saturates at +/-1
      float hnew = z * (hprev - nn) + nn;
      hprev = hnew;

      h_lds[(p + 1) & 1][l] = hnew;        // in-order DS pipe: next step's reads see this
      sb[(size_t)t * 128] = sv0 + hnew;    // 64 lanes -> one coalesced 256 B store
    }
  }
}

// ---------------- windowed causal attention — MFMA flash (r7 version, full 4096-block grid) --
// grid (T/64=8, H=4, N=128), 256 threads = 4 waves; wave w owns q-tile [qbase+w*16, +16).
__global__ __launch_bounds__(256) void attn_kernel(const unsigned short* __restrict__ qkv,
                                                   unsigned short* __restrict__ outp) {
  const int qbase = blockIdx.x * 64;
  const int h = blockIdx.y;
  const int n = blockIdx.z;
  const int tid = threadIdx.x;
  const int w = tid >> 6, lane = tid & 63;
  const int lr = lane & 15, lq = lane >> 4;
  const int ws0 = max(0, qbase - 100);

  const int KROWS = 192;   // staged key rows (>= max window 164, rounded for DMA)
  const int VPITCH = 200;  // VT row pitch in u16 (breaks bank conflicts, 16B-aligned rows)
  const int PPITCH = 40;   // PL row pitch in u16

  __shared__ unsigned short KL[192 * 32];      // K rows [key][d]
  __shared__ unsigned short VT[32 * 200];      // V transposed [d][key]
  __shared__ unsigned short PL[4][16 * 40];    // per-wave P tile [q][k-chunk 32]
  __shared__ float LL[64];                     // per-wave row sums

  const char* qkvb = (const char*)qkv;
  const size_t rowb = ((size_t)(n * 512 + ws0)) * 768;  // window base row, bytes

  // Q A-frag: lane holds Q[q = wq0+lr][d = lq*8..+7] — one 16 B load
  const int wq0 = qbase + w * 16;
  short8 qfrag = *(const short8*)(qkvb + ((size_t)(n * 512 + wq0 + lr)) * 768 + h * 64 + lq * 16);

  // stage K rows via global_load_lds: chunk c (16 B) -> KL byte c*16; row c/4, piece c%4
  #pragma unroll
  for (int it = 0; it < 3; ++it) {
    int c = w * 192 + it * 64 + lane;
    const char* src = qkvb + rowb + (size_t)(c >> 2) * 768 + 256 + h * 64 + (size_t)(c & 3) * 16;
    glds16(src, (char*)KL + w * 3072 + it * 1024);
  }

  // stage V transposed: thread k reads V row, scatters 32 b16 into VT[d][k]
  if (tid < KROWS) {
    const unsigned int* vsrc = (const unsigned int*)(qkvb + rowb + (size_t)tid * 768 + 512 + h * 64);
    #pragma unroll
    for (int u = 0; u < 16; ++u) {
      unsigned int vv = vsrc[u];
      VT[(2 * u) * VPITCH + tid] = (unsigned short)(vv & 0xffff);
      VT[(2 * u + 1) * VPITCH + tid] = (unsigned short)(vv >> 16);
    }
  }
  __syncthreads();  // drains vmcnt (DMA) + lgkm (VT writes) for all waves

  const float SCL2 = 0.17677669529663687f * 1.4426950408889634f;  // 1/sqrt(32) * log2e
  const int lo = max(0, wq0 - 100) - ws0;  // first relevant key (rel), >= 0 always
  const int hi = wq0 + 15 - ws0;           // last relevant key (rel), <= 163
  const int kc0 = lo >> 5, kc1 = hi >> 5;  // 32-key chunks

  f32x4 oacc0 = f32x4{0.f, 0.f, 0.f, 0.f};
  f32x4 oacc1 = f32x4{0.f, 0.f, 0.f, 0.f};
  float lsum[4] = {0.f, 0.f, 0.f, 0.f};
  unsigned short* plw = PL[w];

  for (int kc = kc0; kc <= kc1; ++kc) {
    #pragma unroll
    for (int sub = 0; sub < 2; ++sub) {
      const int kt = kc * 2 + sub;
      short8 kfrag = *(const short8*)(KL + (kt * 16 + lr) * 32 + lq * 8);
      f32x4 s4 = __builtin_amdgcn_mfma_f32_16x16x32_bf16(qfrag, kfrag,
                                                         f32x4{0.f, 0.f, 0.f, 0.f}, 0, 0, 0);
      const int tk = ws0 + kt * 16 + lr;  // this lane's key column
      #pragma unroll
      for (int r = 0; r < 4; ++r) {
        const int tq = wq0 + lq * 4 + r;  // this reg's q row
        bool ok = (tk <= tq) && (tk + 100 >= tq);
        float p = ok ? __builtin_amdgcn_exp2f(s4[r] * SCL2) : 0.f;
        lsum[r] += p;
        plw[(lq * 4 + r) * PPITCH + sub * 16 + lr] = f2bf(p);
      }
    }
    // PV: same-wave DS in-order — reads see the writes above
    short8 pfrag = *(const short8*)(plw + lr * PPITCH + lq * 8);
    short8 vf0 = *(const short8*)(VT + lr * VPITCH + kc * 32 + lq * 8);
    short8 vf1 = *(const short8*)(VT + (16 + lr) * VPITCH + kc * 32 + lq * 8);
    oacc0 = __builtin_amdgcn_mfma_f32_16x16x32_bf16(vf0, pfrag, oacc0, 0, 0, 0);
    oacc1 = __builtin_amdgcn_mfma_f32_16x16x32_bf16(vf1, pfrag, oacc1, 0, 0, 0);
  }

  // row-sum butterfly over the 16 key-columns, then route to q=lr lanes via LDS
  #pragma unroll
  for (int r = 0; r < 4; ++r) {
    float v = lsum[r];
    v += __shfl_xor(v, 1); v += __shfl_xor(v, 2);
    v += __shfl_xor(v, 4); v += __shfl_xor(v, 8);
    lsum[r] = v;
  }
  if (lr == 0) {
    #pragma unroll
    for (int r = 0; r < 4; ++r) LL[w * 16 + lq * 4 + r] = lsum[r];
  }
  float rl = __builtin_amdgcn_rcpf(LL[w * 16 + lr]);  // same-wave DS in-order

  // O^T C-layout: lane holds O[d = dt*16 + lq*4 + r][q = lr] — 4 consecutive d -> dwordx2
  unsigned short* ob = outp + ((size_t)(n * 512 + wq0 + lr)) * 128 + h * 32 + lq * 4;
  {
    unsigned int w0 = ((unsigned int)f2bf(oacc0[1] * rl) << 16) | f2bf(oacc0[0] * rl);
    unsigned int w1 = ((unsigned int)f2bf(oacc0[3] * rl) << 16) | f2bf(oacc0[2] * rl);
    uint2 pk0; pk0.x = w0; pk0.y = w1;
    *(uint2*)ob = pk0;
    unsigned int w2 = ((unsigned int)f2bf(oacc1[1] * rl) << 16) | f2bf(oacc1[0] * rl);
    unsigned int w3 = ((unsigned int)f2bf(oacc1[3] * rl) << 16) | f2bf(oacc1[2] * rl);
    uint2 pk1; pk1.x = w2; pk1.y = w3;
    *(uint2*)(ob + 16) = pk1;
  }
}

// ---------------- host launcher ----------------
extern "C" void kernel_launch(void* const* d_in, const int* in_sizes, int n_in,
                              void* d_out, int out_size, void* d_ws, size_t ws_size,
                              hipStream_t stream) {
  const float* x      = (const float*)d_in[0];
  const float* ln1_g  = (const float*)d_in[1];
  const float* ln1_b  = (const float*)d_in[2];
  const float* wih    = (const float*)d_in[3];
  const float* whh    = (const float*)d_in[4];
  const float* bih    = (const float*)d_in[5];
  const float* bhh    = (const float*)d_in[6];
  const float* ln2_g  = (const float*)d_in[7];
  const float* ln2_b  = (const float*)d_in[8];
  const float* inw    = (const float*)d_in[9];
  const float* inb    = (const float*)d_in[10];
  const float* outw   = (const float*)d_in[11];
  const float* outb   = (const float*)d_in[12];

  char* ws = (char*)d_ws;
  float*          seq   = (float*)ws;                             // 33,554,432 B
  unsigned short* tmpb  = (unsigned short*)(ws + 33554432);       // 16,777,216 B
  unsigned short* big   = (unsigned short*)(ws + 50331648);       // 50,331,648 B
  unsigned short* wih_b = (unsigned short*)(ws + 100663296);      // 3072 elems
  unsigned short* inw_b = wih_b + 3072;                           // 49152 elems
  unsigned short* outw_b = inw_b + 49152;                         // 16384 elems

  // x -> seq + fused ln1 -> tmpb + fused weight conversion
  transpose_in_ln_kernel<<<1024, 256, 0, stream>>>(x, seq, ln1_g, ln1_b, tmpb,
                                                   wih, wih_b, inw, inw_b, outw, outw_b);

  // GRU input projection: [262144][32] x [96][32]^T -> big [(n,t,g)][96]
  gemm_mfma<32, 0><<<dim3(2048, 1), 256, 0, stream>>>(tmpb, wih_b, bih, big, nullptr, 96);

  // GRU scan, seq += h_t  (single-wave blocks, 2 chains/wave)
  gru_kernel<<<256, 64, 0, stream>>>(big, whh, bhh, seq);

  // ln2 -> tmpb
  ln_kernel<<<16384, 256, 0, stream>>>(seq, ln2_g, ln2_b, tmpb);

  // QKV projection: [65536][128] x [384][128]^T -> big [65536][384]
  gemm_mfma<128, 0><<<dim3(512, 3), 256, 0, stream>>>(tmpb, inw_b, inb, big, nullptr, 384);

  // attention -> tmpb (bf16), full 4096-block grid
  attn_kernel<<<dim3(8, 4, 128), 256, 0, stream>>>(big, tmpb);

  // fused transpose-out + out-projection: out = transpose(seq + attn@Wo^T + bo)
  transpose_out_oproj_kernel<<<1024, 256, 0, stream>>>(seq, tmpb, outw_b, outb, (float*)d_out);
}

// Round 13
// 348.968 us; speedup vs baseline: 1.0972x; 1.0124x over previous
//
#include <hip/hip_runtime.h>
#include <hip/hip_bf16.h>
#include <math.h>

// Problem constants: B=2, C=128, T=512, F=64 -> N=B*F=128 sequences, NT=65536 rows.
// GRU: G=4 groups, D=32, 3D=96. MHA: H=4 heads, Dh=32, window=100.
// Workspace layout (needs ~100.8 MB):
//   seq  fp32 [65536][128]  @ 0          (33,554,432 B)  residual stream
//   tmpb bf16 [65536][128]  @ 33554432   (16,777,216 B)  ln1 out, then attn out
//   big  bf16 [65536][384]  @ 50331648   (50,331,648 B)  xp (grouped: [(n,t,g)][96]) then qkv
//   wbuf bf16 weights       @ 100663296  (~137 KB)

typedef __attribute__((ext_vector_type(8))) short short8;
typedef __attribute__((ext_vector_type(4))) float f32x4;
typedef __attribute__((ext_vector_type(2))) float f32x2;

__device__ __forceinline__ float bflo(unsigned int u) { return __uint_as_float(u << 16); }
__device__ __forceinline__ float bfhi(unsigned int u) { return __uint_as_float(u & 0xffff0000u); }
__device__ __forceinline__ float bf2f(unsigned short u) { return __uint_as_float(((unsigned int)u) << 16); }
__device__ __forceinline__ unsigned short f2bf(float f) {
  __hip_bfloat16 h = __float2bfloat16(f);
  return *reinterpret_cast<unsigned short*>(&h);
}

// global -> LDS hardware DMA, 16 B per lane. LDS dest = uniform base + lane*16; global
// source is per-lane (this is how we choose the LDS flattening).
typedef __attribute__((address_space(1))) const unsigned int uint_g;
typedef __attribute__((address_space(3))) unsigned int uint_l;
__device__ __forceinline__ void glds16(const void* g, void* l) {
  __builtin_amdgcn_global_load_lds((uint_g*)g, (uint_l*)l, 16, 0, 0);
}

// ---------------- transpose x[B,C,T,F] -> seq[(b*64+f)][t][c], fused ln1 + weight cvt ----
__global__ __launch_bounds__(256) void transpose_in_ln_kernel(const float* __restrict__ x,
                                                              float* __restrict__ seq,
                                                              const float* __restrict__ gam,
                                                              const float* __restrict__ bet,
                                                              unsigned short* __restrict__ out,
                                                              const float* __restrict__ wih,
                                                              unsigned short* __restrict__ wih_b,
                                                              const float* __restrict__ inw,
                                                              unsigned short* __restrict__ inw_b,
                                                              const float* __restrict__ outw,
                                                              unsigned short* __restrict__ outw_b) {
  // fused weight conversion (3072 + 49152 + 16384 = 68608 elements)
  {
    int g_ = blockIdx.x * 256 + threadIdx.x;
    if (g_ < 3072) wih_b[g_] = f2bf(wih[g_]);
    else if (g_ < 52224) inw_b[g_ - 3072] = f2bf(inw[g_ - 3072]);
    else if (g_ < 68608) outw_b[g_ - 52224] = f2bf(outw[g_ - 52224]);
  }

  __shared__ float tile[128 * 65];
  int b = blockIdx.x >> 9;
  int t = blockIdx.x & 511;
  for (int i = threadIdx.x; i < 128 * 64; i += 256) {
    int c = i >> 6, f = i & 63;
    tile[c * 65 + f] = x[(((size_t)(b * 128 + c)) * 512 + t) * 64 + f];
  }
  __syncthreads();
  for (int i = threadIdx.x; i < 64 * 128; i += 256) {
    int f = i >> 7, c = i & 127;
    seq[(((size_t)(b * 64 + f)) * 512 + t) * 128 + c] = tile[c * 65 + f];
  }

  // fused ln1: thread (f = tid>>2, q = tid&3) reduces channels q*32..q*32+31 of row f
  const int f = threadIdx.x >> 2, q = threadIdx.x & 3;
  float s = 0.f, ss = 0.f;
  #pragma unroll
  for (int u = 0; u < 32; ++u) {
    float v = tile[(q * 32 + u) * 65 + f];
    s += v; ss += v * v;
  }
  s += __shfl_xor(s, 1); s += __shfl_xor(s, 2);
  ss += __shfl_xor(ss, 1); ss += __shfl_xor(ss, 2);
  float mean = s * (1.f / 128.f);
  float var = ss * (1.f / 128.f) - mean * mean;
  float rs = rsqrtf(var + 1e-5f);

  unsigned int* orow = (unsigned int*)(out + (((size_t)(b * 64 + f)) * 512 + t) * 128);
  #pragma unroll
  for (int u = 0; u < 8; ++u) {
    int c0 = q * 32 + u * 4;
    float4 gg = ((const float4*)gam)[c0 >> 2];
    float4 bb = ((const float4*)bet)[c0 >> 2];
    float v0 = tile[(c0 + 0) * 65 + f], v1 = tile[(c0 + 1) * 65 + f];
    float v2 = tile[(c0 + 2) * 65 + f], v3 = tile[(c0 + 3) * 65 + f];
    float o0 = (v0 - mean) * rs * gg.x + bb.x;
    float o1 = (v1 - mean) * rs * gg.y + bb.y;
    float o2 = (v2 - mean) * rs * gg.z + bb.z;
    float o3 = (v3 - mean) * rs * gg.w + bb.w;
    orow[(c0 >> 1) + 0] = ((unsigned int)f2bf(o1) << 16) | (unsigned int)f2bf(o0);
    orow[(c0 >> 1) + 1] = ((unsigned int)f2bf(o3) << 16) | (unsigned int)f2bf(o2);
  }
}

// ---------------- fused transpose-out + out-projection (r12, verified) ----------------
__global__ __launch_bounds__(256) void transpose_out_oproj_kernel(const float* __restrict__ seq,
                                                                  const unsigned short* __restrict__ attn,
                                                                  const unsigned short* __restrict__ outw_b,
                                                                  const float* __restrict__ outb,
                                                                  float* __restrict__ out) {
  __shared__ float tile[128 * 65];
  int b = blockIdx.x >> 9;
  int t = blockIdx.x & 511;
  const int tid = threadIdx.x;
  const int w = tid >> 6, lane = tid & 63;
  const int lr = lane & 15, lq = lane >> 4;

  // residual tile load (coalesced, unchanged from transpose_out)
  for (int i = tid; i < 64 * 128; i += 256) {
    int f = i >> 7, c = i & 127;
    tile[c * 65 + f] = seq[(((size_t)(b * 64 + f)) * 512 + t) * 128 + c];
  }

  // out-projection: wave w owns rows [w*16, +16). Same operand convention as gemm_mfma.
  f32x4 acc[8];
  #pragma unroll
  for (int j = 0; j < 8; ++j) acc[j] = f32x4{0.f, 0.f, 0.f, 0.f};
  const unsigned short* arow = attn + (((size_t)(b * 64 + w * 16 + lr)) * 512 + t) * 128;
  #pragma unroll
  for (int kk = 0; kk < 4; ++kk) {
    short8 af = *(const short8*)(arow + kk * 32 + lq * 8);
    #pragma unroll
    for (int j = 0; j < 8; ++j) {
      short8 wf = *(const short8*)(outw_b + (size_t)(j * 16 + lr) * 128 + kk * 32 + lq * 8);
      acc[j] = __builtin_amdgcn_mfma_f32_16x16x32_bf16(af, wf, acc[j], 0, 0, 0);
    }
  }
  __syncthreads();  // residual tile fully loaded before any lane adds into it

  #pragma unroll
  for (int j = 0; j < 8; ++j) {
    int col = j * 16 + lr;
    float bb = outb[col];
    #pragma unroll
    for (int r = 0; r < 4; ++r) {
      int f = w * 16 + lq * 4 + r;        // one writer per (col,f)
      tile[col * 65 + f] += acc[j][r] + bb;
    }
  }
  __syncthreads();

  for (int i = tid; i < 128 * 64; i += 256) {
    int c = i >> 6, f = i & 63;
    out[(((size_t)(b * 128 + c)) * 512 + t) * 64 + f] = tile[c * 65 + f];
  }
}

// ---------------- MFMA GEMM (used for GRU input projection only) ----------------
// A bf16 [M][K], W bf16 [Ncols][K]. Stores bf16 (stride Ncols).
template <int K>
__global__ __launch_bounds__(256) void gemm_mfma(const unsigned short* __restrict__ A,
                                                 const unsigned short* __restrict__ W,
                                                 const float* __restrict__ bias,
                                                 unsigned short* __restrict__ outB, int Ncols) {
  const int tid = threadIdx.x;
  const int wave = tid >> 6, lane = tid & 63;
  const int wy = wave >> 1, wx = wave & 1;
  const int lr = lane & 15, lq = lane >> 4;
  const int m0 = blockIdx.x * 128 + wy * 64;
  const int n0 = blockIdx.y * 128 + wx * 64;

  f32x4 acc[4][4];
  #pragma unroll
  for (int i = 0; i < 4; ++i)
    #pragma unroll
    for (int j = 0; j < 4; ++j) acc[i][j] = f32x4{0.f, 0.f, 0.f, 0.f};

  const short8 zfrag = short8{0, 0, 0, 0, 0, 0, 0, 0};

  #pragma unroll
  for (int kk = 0; kk < K; kk += 32) {
    short8 af[4], bfq[4];
    #pragma unroll
    for (int i = 0; i < 4; ++i)
      af[i] = *(const short8*)(A + (size_t)(m0 + i * 16 + lr) * K + kk + lq * 8);
    #pragma unroll
    for (int j = 0; j < 4; ++j) {
      int wr = n0 + j * 16 + lr;
      bfq[j] = (wr < Ncols) ? *(const short8*)(W + (size_t)wr * K + kk + lq * 8) : zfrag;
    }
    #pragma unroll
    for (int i = 0; i < 4; ++i)
      #pragma unroll
      for (int j = 0; j < 4; ++j)
        acc[i][j] = __builtin_amdgcn_mfma_f32_16x16x32_bf16(af[i], bfq[j], acc[i][j], 0, 0, 0);
  }

  #pragma unroll
  for (int j = 0; j < 4; ++j) {
    int col = n0 + j * 16 + lr;
    if (col < Ncols) {
      float bb = bias[col];
      #pragma unroll
      for (int i = 0; i < 4; ++i) {
        #pragma unroll
        for (int r = 0; r < 4; ++r) {
          int row = m0 + i * 16 + lq * 4 + r;
          outB[(size_t)row * Ncols + col] = f2bf(acc[i][j][r] + bb);
        }
      }
    }
  }
}

// ---------------- fused ln2 + QKV projection ----------------
// Round 12 consolidation: the qkv gemm's A-tile is 128 rows x 128 ch — one LN unit per row.
// Phase 1: load the seq tile fp32, LN per row (wave w owns rows w*32..+31; lanes l and l^32
// split the 128 channels, one shfl_xor(32) combine — math identical to the old ln_kernel),
// write normalized bf16 into LDS [128][132] (pad 132 breaks the 16-row stride conflict down
// to light 4-way). Phase 2: standard MFMA loop with A-fragments from LDS; W/output unchanged.
// Eliminates the standalone ln2 kernel (~9 us), its launch gap, and 32 MB of tmpb traffic.
// LN recomputed per blockIdx.y (3x) — cheap VALU. Numerics identical (fp32 LN -> bf16).
#define APITCH 132
__global__ __launch_bounds__(256) void gemm_ln_qkv(const float* __restrict__ seq,
                                                   const float* __restrict__ gam,
                                                   const float* __restrict__ bet,
                                                   const unsigned short* __restrict__ W,
                                                   const float* __restrict__ bias,
                                                   unsigned short* __restrict__ outB) {
  const int tid = threadIdx.x;
  const int wave = tid >> 6, lane = tid & 63;
  const int wy = wave >> 1, wx = wave & 1;
  const int lr = lane & 15, lq = lane >> 4;
  const int m0 = blockIdx.x * 128;
  const int n0 = blockIdx.y * 128 + wx * 64;

  __shared__ unsigned short ALds[128 * APITCH];

  // ---- phase 1: LN of rows m0..m0+127 into ALds ----
  {
    const int row = wave * 32 + (lane & 31);   // local row 0..127
    const int half = lane >> 5;                // channel half 0/1
    const float4* src = (const float4*)(seq + (size_t)(m0 + row) * 128 + half * 64);
    float4 v[16];
    float s = 0.f, ss = 0.f;
    #pragma unroll
    for (int u = 0; u < 16; ++u) {
      v[u] = src[u];
      s += v[u].x + v[u].y + v[u].z + v[u].w;
      ss += v[u].x * v[u].x + v[u].y * v[u].y + v[u].z * v[u].z + v[u].w * v[u].w;
    }
    s += __shfl_xor(s, 32);
    ss += __shfl_xor(ss, 32);
    float mean = s * (1.f / 128.f);
    float var = ss * (1.f / 128.f) - mean * mean;
    float rs = rsqrtf(var + 1e-5f);
    unsigned int* dst = (unsigned int*)(ALds + row * APITCH + half * 64);
    #pragma unroll
    for (int u = 0; u < 16; ++u) {
      int c0 = half * 64 + u * 4;
      float4 gg = ((const float4*)gam)[c0 >> 2];
      float4 bb = ((const float4*)bet)[c0 >> 2];
      float o0 = (v[u].x - mean) * rs * gg.x + bb.x;
      float o1 = (v[u].y - mean) * rs * gg.y + bb.y;
      float o2 = (v[u].z - mean) * rs * gg.z + bb.z;
      float o3 = (v[u].w - mean) * rs * gg.w + bb.w;
      dst[2 * u + 0] = ((unsigned int)f2bf(o1) << 16) | (unsigned int)f2bf(o0);
      dst[2 * u + 1] = ((unsigned int)f2bf(o3) << 16) | (unsigned int)f2bf(o2);
    }
  }
  __syncthreads();

  // ---- phase 2: MFMA from LDS A-tile ----
  f32x4 acc[4][4];
  #pragma unroll
  for (int i = 0; i < 4; ++i)
    #pragma unroll
    for (int j = 0; j < 4; ++j) acc[i][j] = f32x4{0.f, 0.f, 0.f, 0.f};

  #pragma unroll
  for (int kk = 0; kk < 128; kk += 32) {
    short8 af[4], bfq[4];
    #pragma unroll
    for (int i = 0; i < 4; ++i)
      af[i] = *(const short8*)(ALds + (wy * 64 + i * 16 + lr) * APITCH + kk + lq * 8);
    #pragma unroll
    for (int j = 0; j < 4; ++j) {
      int wr = n0 + j * 16 + lr;   // < 384 always
      bfq[j] = *(const short8*)(W + (size_t)wr * 128 + kk + lq * 8);
    }
    #pragma unroll
    for (int i = 0; i < 4; ++i)
      #pragma unroll
      for (int j = 0; j < 4; ++j)
        acc[i][j] = __builtin_amdgcn_mfma_f32_16x16x32_bf16(af[i], bfq[j], acc[i][j], 0, 0, 0);
  }

  #pragma unroll
  for (int j = 0; j < 4; ++j) {
    int col = n0 + j * 16 + lr;
    float bb = bias[col];
    #pragma unroll
    for (int i = 0; i < 4; ++i) {
      #pragma unroll
      for (int r = 0; r < 4; ++r) {
        int row = m0 + wy * 64 + i * 16 + lq * 4 + r;
        outB[(size_t)row * 384 + col] = f2bf(acc[i][j][r] + bb);
      }
    }
  }
}

// ---------------- grouped GRU scan over T=512 — LDS-DMA double-buffered chunks ----------------
// Best measured variant (138.5 us, rounds 6/7/10/11/12). Do not restructure without disasm
// evidence (r8 XOR-systolic 145.9, r9 split-K 151.1 both regressed; ~650 cyc/step invariant).
__global__ __launch_bounds__(64, 1) void gru_kernel(const unsigned short* __restrict__ xp,
                                                    const float* __restrict__ whh,
                                                    const float* __restrict__ bhh,
                                                    float* __restrict__ seq) {
  const int l = threadIdx.x;
  const int half = l >> 5, d = l & 31;
  const int blk = blockIdx.x;           // 0..255
  const int chain = blk * 2 + half;     // chains 2b,2b+1 share n
  const int n = chain >> 2;
  const int g0 = (blk * 2) & 3;

  const float LOG2E = 1.4426950408889634f;
  const float T2LOG2E = 2.8853900817779268f;

  __shared__ __align__(16) unsigned char stage[2][6144];  // per buf: xp0 2K | xp1 2K | seq 2K
  __shared__ __align__(16) float h_lds[2][64];
  h_lds[0][l] = 0.f;

  f32x2 wr2[16], wz2[16], wn2[16];
  #pragma unroll
  for (int u = 0; u < 16; ++u) {
    float2 a = *(const float2*)(whh + (size_t)d * 32 + u * 2);
    float2 b = *(const float2*)(whh + (size_t)(32 + d) * 32 + u * 2);
    float2 c = *(const float2*)(whh + (size_t)(64 + d) * 32 + u * 2);
    wr2[u] = f32x2{a.x * LOG2E, a.y * LOG2E};
    wz2[u] = f32x2{b.x * LOG2E, b.y * LOG2E};
    wn2[u] = f32x2{c.x * T2LOG2E, c.y * T2LOG2E};
  }
  // Pins are LOAD-BEARING: they keep the loop free of remat vmem loads, which would corrupt
  // the vmcnt counts below.
  #pragma unroll
  for (int u = 0; u < 16; ++u)
    asm volatile("" : "+v"(wr2[u]), "+v"(wz2[u]), "+v"(wn2[u]));

  float br = bhh[d] * LOG2E, bz = bhh[32 + d] * LOG2E, bn = bhh[64 + d] * T2LOG2E;
  asm volatile("" : "+v"(br), "+v"(bz), "+v"(bn));

  const char* xg = (const char*)xp;
  const size_t cb0 = ((size_t)n * 2048 + g0) * 192;
  const size_t cb1 = ((size_t)n * 2048 + g0 + 1) * 192;
  const int fa = l * 16;
  const int oxa = (fa / 192) * 768 + (fa % 192);
  const int fb = 1024 + l * 16;
  const int oxb = (fb / 192) * 768 + (fb % 192);
  const char* px0a = xg + cb0 + oxa;
  const char* px0b = xg + cb0 + oxb;
  const char* px1a = xg + cb1 + oxa;
  const char* px1b = xg + cb1 + oxb;
  const int osa = (l >> 4) * 512 + (l & 15) * 16;
  const size_t sqb0 = ((size_t)n * 512 * 128 + (size_t)g0 * 32) * 4;
  const char* psa = (const char*)seq + sqb0 + osa;
  const char* psb = psa + 2048;  // rows 4..7

  float* sb = seq + (size_t)n * 512 * 128 + g0 * 32 + l;  // per-lane output addr (t=0)

  glds16(px0a, stage[0] + 0);
  glds16(px0b, stage[0] + 1024);
  glds16(px1a, stage[0] + 2048);
  glds16(px1b, stage[0] + 3072);
  glds16(psa,  stage[0] + 4096);
  glds16(psb,  stage[0] + 5120);

  float hprev = 0.f;

  for (int c = 0; c < 64; ++c) {
    const int cur = c & 1;
    if (c < 63) {
      const size_t xo = (size_t)(c + 1) * 6144;
      const size_t so = (size_t)(c + 1) * 4096;
      unsigned char* nb = stage[cur ^ 1];
      glds16(px0a + xo, nb + 0);
      glds16(px0b + xo, nb + 1024);
      glds16(px1a + xo, nb + 2048);
      glds16(px1b + xo, nb + 3072);
      glds16(psa + so,  nb + 4096);
      glds16(psb + so,  nb + 5120);
    }
    __builtin_amdgcn_sched_barrier(0);
    if (c == 0)       asm volatile("s_waitcnt vmcnt(6)" ::: "memory");
    else if (c == 63) asm volatile("s_waitcnt vmcnt(8)" ::: "memory");
    else              asm volatile("s_waitcnt vmcnt(14)" ::: "memory");
    __builtin_amdgcn_sched_barrier(0);

    const unsigned char* scur = stage[cur];
    #pragma unroll
    for (int p = 0; p < 8; ++p) {
      const int t = c * 8 + p;

      const f32x4* hsrc = (const f32x4*)&h_lds[p & 1][half * 32];
      f32x2 ar0 = f32x2{br, 0.f}, ar1 = f32x2{0.f, 0.f};
      f32x2 az0 = f32x2{bz, 0.f}, az1 = f32x2{0.f, 0.f};
      f32x2 an0 = f32x2{bn, 0.f}, an1 = f32x2{0.f, 0.f};
      #pragma unroll
      for (int u = 0; u < 8; ++u) {
        f32x4 h4 = hsrc[u];
        f32x2 hlo = f32x2{h4.x, h4.y};
        f32x2 hhi = f32x2{h4.z, h4.w};
        ar0 += wr2[2 * u] * hlo; ar1 += wr2[2 * u + 1] * hhi;
        az0 += wz2[2 * u] * hlo; az1 += wz2[2 * u + 1] * hhi;
        an0 += wn2[2 * u] * hlo; an1 += wn2[2 * u + 1] * hhi;
      }
      f32x2 arv = ar0 + ar1, azv = az0 + az1, anv = an0 + an1;
      float accr = arv.x + arv.y;
      float accz = azv.x + azv.y;
      float accn = anv.x + anv.y;

      const unsigned short* xrow = (const unsigned short*)(scur + half * 2048 + p * 192);
      float xr = bf2f(xrow[d]) * LOG2E;
      float xz = bf2f(xrow[32 + d]) * LOG2E;
      float xn2 = bf2f(xrow[64 + d]) * T2LOG2E;
      float sv0 = *(const float*)(scur + 4096 + p * 256 + (l << 2));

      float r = __builtin_amdgcn_rcpf(1.f + __builtin_amdgcn_exp2f(-(xr + accr)));
      float z = __builtin_amdgcn_rcpf(1.f + __builtin_amdgcn_exp2f(-(xz + accz)));
      float e2 = __builtin_amdgcn_exp2f(xn2 + r * accn);
      float nn = 1.f - 2.f * __builtin_amdgcn_rcpf(e2 + 1.f);  // tanh, saturates at +/-1
      float hnew = z * (hprev - nn) + nn;
      hprev = hnew;

      h_lds[(p + 1) & 1][l] = hnew;        // in-order DS pipe: next step's reads see this
      sb[(size_t)t * 128] = sv0 + hnew;    // 64 lanes -> one coalesced 256 B store
    }
  }
}

// ---------------- windowed causal attention — MFMA flash (r7 version, full 4096-block grid) --
// grid (T/64=8, H=4, N=128), 256 threads = 4 waves; wave w owns q-tile [qbase+w*16, +16).
__global__ __launch_bounds__(256) void attn_kernel(const unsigned short* __restrict__ qkv,
                                                   unsigned short* __restrict__ outp) {
  const int qbase = blockIdx.x * 64;
  const int h = blockIdx.y;
  const int n = blockIdx.z;
  const int tid = threadIdx.x;
  const int w = tid >> 6, lane = tid & 63;
  const int lr = lane & 15, lq = lane >> 4;
  const int ws0 = max(0, qbase - 100);

  const int KROWS = 192;   // staged key rows (>= max window 164, rounded for DMA)
  const int VPITCH = 200;  // VT row pitch in u16 (breaks bank conflicts, 16B-aligned rows)
  const int PPITCH = 40;   // PL row pitch in u16

  __shared__ unsigned short KL[192 * 32];      // K rows [key][d]
  __shared__ unsigned short VT[32 * 200];      // V transposed [d][key]
  __shared__ unsigned short PL[4][16 * 40];    // per-wave P tile [q][k-chunk 32]
  __shared__ float LL[64];                     // per-wave row sums

  const char* qkvb = (const char*)qkv;
  const size_t rowb = ((size_t)(n * 512 + ws0)) * 768;  // window base row, bytes

  // Q A-frag: lane holds Q[q = wq0+lr][d = lq*8..+7] — one 16 B load
  const int wq0 = qbase + w * 16;
  short8 qfrag = *(const short8*)(qkvb + ((size_t)(n * 512 + wq0 + lr)) * 768 + h * 64 + lq * 16);

  // stage K rows via global_load_lds: chunk c (16 B) -> KL byte c*16; row c/4, piece c%4
  #pragma unroll
  for (int it = 0; it < 3; ++it) {
    int c = w * 192 + it * 64 + lane;
    const char* src = qkvb + rowb + (size_t)(c >> 2) * 768 + 256 + h * 64 + (size_t)(c & 3) * 16;
    glds16(src, (char*)KL + w * 3072 + it * 1024);
  }

  // stage V transposed: thread k reads V row, scatters 32 b16 into VT[d][k]
  if (tid < KROWS) {
    const unsigned int* vsrc = (const unsigned int*)(qkvb + rowb + (size_t)tid * 768 + 512 + h * 64);
    #pragma unroll
    for (int u = 0; u < 16; ++u) {
      unsigned int vv = vsrc[u];
      VT[(2 * u) * VPITCH + tid] = (unsigned short)(vv & 0xffff);
      VT[(2 * u + 1) * VPITCH + tid] = (unsigned short)(vv >> 16);
    }
  }
  __syncthreads();  // drains vmcnt (DMA) + lgkm (VT writes) for all waves

  const float SCL2 = 0.17677669529663687f * 1.4426950408889634f;  // 1/sqrt(32) * log2e
  const int lo = max(0, wq0 - 100) - ws0;  // first relevant key (rel), >= 0 always
  const int hi = wq0 + 15 - ws0;           // last relevant key (rel), <= 163
  const int kc0 = lo >> 5, kc1 = hi >> 5;  // 32-key chunks

  f32x4 oacc0 = f32x4{0.f, 0.f, 0.f, 0.f};
  f32x4 oacc1 = f32x4{0.f, 0.f, 0.f, 0.f};
  float lsum[4] = {0.f, 0.f, 0.f, 0.f};
  unsigned short* plw = PL[w];

  for (int kc = kc0; kc <= kc1; ++kc) {
    #pragma unroll
    for (int sub = 0; sub < 2; ++sub) {
      const int kt = kc * 2 + sub;
      short8 kfrag = *(const short8*)(KL + (kt * 16 + lr) * 32 + lq * 8);
      f32x4 s4 = __builtin_amdgcn_mfma_f32_16x16x32_bf16(qfrag, kfrag,
                                                         f32x4{0.f, 0.f, 0.f, 0.f}, 0, 0, 0);
      const int tk = ws0 + kt * 16 + lr;  // this lane's key column
      #pragma unroll
      for (int r = 0; r < 4; ++r) {
        const int tq = wq0 + lq * 4 + r;  // this reg's q row
        bool ok = (tk <= tq) && (tk + 100 >= tq);
        float p = ok ? __builtin_amdgcn_exp2f(s4[r] * SCL2) : 0.f;
        lsum[r] += p;
        plw[(lq * 4 + r) * PPITCH + sub * 16 + lr] = f2bf(p);
      }
    }
    // PV: same-wave DS in-order — reads see the writes above
    short8 pfrag = *(const short8*)(plw + lr * PPITCH + lq * 8);
    short8 vf0 = *(const short8*)(VT + lr * VPITCH + kc * 32 + lq * 8);
    short8 vf1 = *(const short8*)(VT + (16 + lr) * VPITCH + kc * 32 + lq * 8);
    oacc0 = __builtin_amdgcn_mfma_f32_16x16x32_bf16(vf0, pfrag, oacc0, 0, 0, 0);
    oacc1 = __builtin_amdgcn_mfma_f32_16x16x32_bf16(vf1, pfrag, oacc1, 0, 0, 0);
  }

  // row-sum butterfly over the 16 key-columns, then route to q=lr lanes via LDS
  #pragma unroll
  for (int r = 0; r < 4; ++r) {
    float v = lsum[r];
    v += __shfl_xor(v, 1); v += __shfl_xor(v, 2);
    v += __shfl_xor(v, 4); v += __shfl_xor(v, 8);
    lsum[r] = v;
  }
  if (lr == 0) {
    #pragma unroll
    for (int r = 0; r < 4; ++r) LL[w * 16 + lq * 4 + r] = lsum[r];
  }
  float rl = __builtin_amdgcn_rcpf(LL[w * 16 + lr]);  // same-wave DS in-order

  // O^T C-layout: lane holds O[d = dt*16 + lq*4 + r][q = lr] — 4 consecutive d -> dwordx2
  unsigned short* ob = outp + ((size_t)(n * 512 + wq0 + lr)) * 128 + h * 32 + lq * 4;
  {
    unsigned int w0 = ((unsigned int)f2bf(oacc0[1] * rl) << 16) | f2bf(oacc0[0] * rl);
    unsigned int w1 = ((unsigned int)f2bf(oacc0[3] * rl) << 16) | f2bf(oacc0[2] * rl);
    uint2 pk0; pk0.x = w0; pk0.y = w1;
    *(uint2*)ob = pk0;
    unsigned int w2 = ((unsigned int)f2bf(oacc1[1] * rl) << 16) | f2bf(oacc1[0] * rl);
    unsigned int w3 = ((unsigned int)f2bf(oacc1[3] * rl) << 16) | f2bf(oacc1[2] * rl);
    uint2 pk1; pk1.x = w2; pk1.y = w3;
    *(uint2*)(ob + 16) = pk1;
  }
}

// ---------------- host launcher ----------------
extern "C" void kernel_launch(void* const* d_in, const int* in_sizes, int n_in,
                              void* d_out, int out_size, void* d_ws, size_t ws_size,
                              hipStream_t stream) {
  const float* x      = (const float*)d_in[0];
  const float* ln1_g  = (const float*)d_in[1];
  const float* ln1_b  = (const float*)d_in[2];
  const float* wih    = (const float*)d_in[3];
  const float* whh    = (const float*)d_in[4];
  const float* bih    = (const float*)d_in[5];
  const float* bhh    = (const float*)d_in[6];
  const float* ln2_g  = (const float*)d_in[7];
  const float* ln2_b  = (const float*)d_in[8];
  const float* inw    = (const float*)d_in[9];
  const float* inb    = (const float*)d_in[10];
  const float* outw   = (const float*)d_in[11];
  const float* outb   = (const float*)d_in[12];

  char* ws = (char*)d_ws;
  float*          seq   = (float*)ws;                             // 33,554,432 B
  unsigned short* tmpb  = (unsigned short*)(ws + 33554432);       // 16,777,216 B
  unsigned short* big   = (unsigned short*)(ws + 50331648);       // 50,331,648 B
  unsigned short* wih_b = (unsigned short*)(ws + 100663296);      // 3072 elems
  unsigned short* inw_b = wih_b + 3072;                           // 49152 elems
  unsigned short* outw_b = inw_b + 49152;                         // 16384 elems

  // x -> seq + fused ln1 -> tmpb + fused weight conversion
  transpose_in_ln_kernel<<<1024, 256, 0, stream>>>(x, seq, ln1_g, ln1_b, tmpb,
                                                   wih, wih_b, inw, inw_b, outw, outw_b);

  // GRU input projection: [262144][32] x [96][32]^T -> big [(n,t,g)][96]
  gemm_mfma<32><<<dim3(2048, 1), 256, 0, stream>>>(tmpb, wih_b, bih, big, 96);

  // GRU scan, seq += h_t  (single-wave blocks, 2 chains/wave)
  gru_kernel<<<256, 64, 0, stream>>>(big, whh, bhh, seq);

  // fused ln2 + QKV projection: ln(seq) [65536][128] x [384][128]^T -> big [65536][384]
  gemm_ln_qkv<<<dim3(512, 3), 256, 0, stream>>>(seq, ln2_g, ln2_b, inw_b, inb, big);

  // attention -> tmpb (bf16), full 4096-block grid
  attn_kernel<<<dim3(8, 4, 128), 256, 0, stream>>>(big, tmpb);

  // fused transpose-out + out-projection: out = transpose(seq + attn@Wo^T + bo)
  transpose_out_oproj_kernel<<<1024, 256, 0, stream>>>(seq, tmpb, outw_b, outb, (float*)d_out);
}